// Round 6
// baseline (94.803 us; speedup 1.0000x reference)
//
#include <hip/hip_runtime.h>
#include <math.h>

#define BATCH 256
#define FEAT 128
#define CAP 100000
#define ROWF 168
#define K 5
#define CHUNKK 256
#define NBLK 391            // 391*256 = 100096 >= CAP
#define NCAND (NBLK*K)      // 1955
#define CPT 8               // ceil(1955/256)

// out layout (floats): retrieved [0,215040) | top_sims | valid_mask | top_idx
#define OUT_SIMS 215040
#define OUT_MASK 216320
#define OUT_IDX  217600

// ws layout (float units)
#define WS_QN    0          // 256*128 f32 normalized queries (exact rescore)
#define WS_QF    32768      // 4096 uint4 = bf16 B-fragments
#define WS_PSIM  49152      // 256*1955 f32
#define WS_PIDX  549632     // 256*1955 i32

typedef __attribute__((ext_vector_type(8))) short short8;
typedef __attribute__((ext_vector_type(4))) float f32x4;

#define BET(vs,vi,ss,ii) ((vs) > (ss) || ((vs) == (ss) && (vi) < (ii)))

__device__ __forceinline__ unsigned short f2bf(float f) {
  unsigned u = __float_as_uint(f);
  u += 0x7fffu + ((u >> 16) & 1u);     // RNE
  return (unsigned short)(u >> 16);
}
__device__ __forceinline__ unsigned pack2(float a, float b) {
  return (unsigned)f2bf(a) | ((unsigned)f2bf(b) << 16);
}

// flat bubble-insert: replace slot 4 then compare-exchange up.
// strict '>' + ascending-idx stream == jax tie-break (lower idx first).
__device__ __forceinline__ void ins2(float v, int k, float (&s)[5], int (&i)[5]) {
  bool c = v > s[4];
  s[4] = c ? v : s[4];  i[4] = c ? k : i[4];
  #pragma unroll
  for (int j = 4; j >= 1; --j) {
    bool d = s[j] > s[j-1];
    float hs = d ? s[j] : s[j-1];
    float ls = d ? s[j-1] : s[j];
    int   hi = d ? i[j] : i[j-1];
    int   li = d ? i[j-1] : i[j];
    s[j-1]=hs; s[j]=ls; i[j-1]=hi; i[j]=li;
  }
}
// cross-lane merge insert (arbitrary idx order -> explicit tie-break)
__device__ __forceinline__ void ins_cmp(float v, int k, float (&s)[5], int (&i)[5]) {
  if (BET(v,k,s[4],i[4])) {
    if (BET(v,k,s[3],i[3])) { s[4]=s[3]; i[4]=i[3];
      if (BET(v,k,s[2],i[2])) { s[3]=s[2]; i[3]=i[2];
        if (BET(v,k,s[1],i[1])) { s[2]=s[1]; i[2]=i[1];
          if (BET(v,k,s[0],i[0])) { s[1]=s[0]; i[1]=i[0]; s[0]=v; i[0]=k; }
          else { s[1]=v; i[1]=k; } }
        else { s[2]=v; i[2]=k; } }
      else { s[3]=v; i[3]=k; } }
    else { s[4]=v; i[4]=k; }
  }
}

// grid 16 (q-groups of 16), block 256. Writes f32 qn + bf16 B-fragments.
__global__ __launch_bounds__(256) void prep_q(const float* __restrict__ q,
                                              float* __restrict__ qn,
                                              uint4* __restrict__ qF) {
  int tid = threadIdx.x, qg = blockIdx.x;
  int qi = tid >> 4;             // query in group (0..15)
  int d0 = (tid & 15) * 8;
  int q_ = qg*16 + qi;
  const float4* src = reinterpret_cast<const float4*>(q + (size_t)q_*FEAT + d0);
  float4 v0 = src[0], v1 = src[1];
  float ss = v0.x*v0.x + v0.y*v0.y + v0.z*v0.z + v0.w*v0.w
           + v1.x*v1.x + v1.y*v1.y + v1.z*v1.z + v1.w*v1.w;
  ss += __shfl_xor(ss,1); ss += __shfl_xor(ss,2);
  ss += __shfl_xor(ss,4); ss += __shfl_xor(ss,8);
  float inv = 1.0f / fmaxf(sqrtf(ss), 1e-12f);
  v0.x*=inv; v0.y*=inv; v0.z*=inv; v0.w*=inv;
  v1.x*=inv; v1.y*=inv; v1.z*=inv; v1.w*=inv;
  float4* dst = reinterpret_cast<float4*>(qn + (size_t)q_*FEAT + d0);
  dst[0] = v0; dst[1] = v1;
  uint4 pk;
  pk.x = pack2(v0.x,v0.y); pk.y = pack2(v0.z,v0.w);
  pk.z = pack2(v1.x,v1.y); pk.w = pack2(v1.z,v1.w);
  int s_ = d0 >> 5, lg = (d0 >> 3) & 3;
  qF[((qg*4 + s_)*64) + lg*16 + qi] = pk;
}

// grid NBLK, block 1024 (16 waves; wave w owns query-group w).
// One-shot staging of the 256-key chunk into LDS bf16 fragments, then
// pure LDS->MFMA loop with cheap group-reject top-5 insert.
__global__ __launch_bounds__(1024, 8) void gemm_topk3(
    const float* __restrict__ keys, const int* __restrict__ ts,
    const int* __restrict__ gstep, const uint4* __restrict__ qF,
    float* __restrict__ psim, int* __restrict__ pidx) {
  __shared__ uint4 lds_kf[16*4*64];    // 64 KB: [tile][s][lg*16+k15]
  int tid = threadIdx.x;
  int w = tid >> 6, lane = tid & 63;
  int chunk = blockIdx.x;
  int kbase = chunk * CHUNKK;
  int gstep0 = gstep[0];

  // B fragments for this wave's query group (16 regs, constant-indexed)
  short8 qf[4];
  #pragma unroll
  for (int s_ = 0; s_ < 4; ++s_)
    qf[s_] = __builtin_bit_cast(short8, qF[(w*4 + s_)*64 + lane]);

  // stage: 1024 threads x 4 iters cover 256 keys x 128 dims
  #pragma unroll
  for (int it = 0; it < 4; ++it) {
    int kl = it*64 + (tid >> 4);       // local key 0..255
    int dp = tid & 15;                 // 8-dim slice
    int gk = kbase + kl;
    float4 v0 = {0,0,0,0}, v1 = {0,0,0,0};
    if (gk < CAP) {
      const float4* kp = reinterpret_cast<const float4*>(keys + (size_t)gk*FEAT + dp*8);
      v0 = kp[0]; v1 = kp[1];
    }
    float ss = v0.x*v0.x+v0.y*v0.y+v0.z*v0.z+v0.w*v0.w
             + v1.x*v1.x+v1.y*v1.y+v1.z*v1.z+v1.w*v1.w;
    ss += __shfl_xor(ss,1); ss += __shfl_xor(ss,2);
    ss += __shfl_xor(ss,4); ss += __shfl_xor(ss,8);
    float scl = 0.0f;
    if (gk < CAP) {
      float age = (float)(gstep0 - ts[gk]);
      scl = exp2f(age * -0.00723157f) / fmaxf(sqrtf(ss), 1e-12f);  // approx path only
    }
    uint4 pk;
    pk.x = pack2(v0.x*scl, v0.y*scl); pk.y = pack2(v0.z*scl, v0.w*scl);
    pk.z = pack2(v1.x*scl, v1.y*scl); pk.w = pack2(v1.z*scl, v1.w*scl);
    int tile = kl >> 4, k15 = kl & 15, s_ = dp >> 2, lg = dp & 3;
    lds_kf[(tile*4 + s_)*64 + lg*16 + k15] = pk;
  }
  __syncthreads();

  float s[5] = {-INFINITY,-INFINITY,-INFINITY,-INFINITY,-INFINITY};
  int   ix[5] = {0,0,0,0,0};

  #pragma unroll 2
  for (int t = 0; t < 16; ++t) {
    f32x4 acc = {0.f,0.f,0.f,0.f};
    #pragma unroll
    for (int s_ = 0; s_ < 4; ++s_) {
      short8 a = __builtin_bit_cast(short8, lds_kf[(t*4 + s_)*64 + lane]);
      acc = __builtin_amdgcn_mfma_f32_16x16x32_bf16(a, qf[s_], acc, 0,0,0);
    }
    // C/D: col=lane&15 (query), row=(lane>>4)*4+r (key)
    float mx = fmaxf(fmaxf(acc[0],acc[1]), fmaxf(acc[2],acc[3]));
    if (mx > s[4]) {                    // group reject: one branch per tile
      int kb = kbase + t*16 + (lane>>4)*4;
      ins2(acc[0], kb+0, s, ix);
      ins2(acc[1], kb+1, s, ix);
      ins2(acc[2], kb+2, s, ix);
      ins2(acc[3], kb+3, s, ix);
    }
  }

  // merge the 4 lane-groups (disjoint key subsets) for each query col
  #pragma unroll
  for (int off = 16; off <= 32; off <<= 1) {
    float ps[5]; int pi[5];
    #pragma unroll
    for (int j=0;j<5;++j){ ps[j]=__shfl_xor(s[j],off); pi[j]=__shfl_xor(ix[j],off); }
    #pragma unroll
    for (int j=0;j<5;++j) ins_cmp(ps[j], pi[j], s, ix);
  }

  if (lane < 16) {
    int q = w*16 + lane;
    int base = q*NCAND + chunk*K;
    #pragma unroll
    for (int j=0;j<K;++j) { psim[base+j]=s[j]; pidx[base+j]=ix[j]; }
  }
}

// grid 256 (1/query), block 256: approx top-5 -> margin filter -> exact rescore
__global__ __launch_bounds__(256) void merge_rescore(
    const float* __restrict__ psim, const int* __restrict__ pidx,
    const float* __restrict__ keys, const float* __restrict__ qn,
    const int* __restrict__ ts, const int* __restrict__ gstep,
    const float* __restrict__ values, float* __restrict__ out) {
  int q = blockIdx.x, tid = threadIdx.x;
  int gstep0 = gstep[0];
  float cs[CPT]; int ci[CPT];
  #pragma unroll
  for (int j=0;j<CPT;++j) {
    int c = tid + j*256;
    if (c < NCAND) { cs[j]=psim[q*NCAND+c]; ci[j]=pidx[q*NCAND+c]; }
    else { cs[j]=-INFINITY; ci[j]=0x7fffffff; }
  }

  __shared__ float rs_[4]; __shared__ int ri_[4];
  __shared__ float wS; __shared__ int wI;
  unsigned taken = 0;
  float s5a = 0.f;
  for (int r=0;r<K;++r) {
    float bs=-INFINITY; int bi=0x7fffffff;
    #pragma unroll
    for (int j=0;j<CPT;++j) {
      bool live = !((taken>>j)&1u);
      bool bet = live && BET(cs[j],ci[j],bs,bi);
      bs = bet?cs[j]:bs; bi = bet?ci[j]:bi;
    }
    #pragma unroll
    for (int o=1;o<64;o<<=1) {
      float os=__shfl_xor(bs,o); int oi=__shfl_xor(bi,o);
      if (BET(os,oi,bs,bi)) { bs=os; bi=oi; }
    }
    if ((tid&63)==0){ rs_[tid>>6]=bs; ri_[tid>>6]=bi; }
    __syncthreads();
    if (tid==0) {
      float fs=rs_[0]; int fi=ri_[0];
      #pragma unroll
      for (int ww=1;ww<4;++ww) if (BET(rs_[ww],ri_[ww],fs,fi)) { fs=rs_[ww]; fi=ri_[ww]; }
      wS=fs; wI=fi;
    }
    __syncthreads();
    float fs=wS; int fi=wI;
    #pragma unroll
    for (int j=0;j<CPT;++j) if (ci[j]==fi) taken |= (1u<<j);
    if (r==K-1) s5a = fs;
  }

  // collect everything within margin of the 5th approx (bf16 err << 8e-3)
  float thresh = s5a - 0.008f;
  __shared__ int cnt; __shared__ int clx[32];
  if (tid==0) cnt=0;
  __syncthreads();
  #pragma unroll
  for (int j=0;j<CPT;++j)
    if (cs[j] >= thresh) { int p = atomicAdd(&cnt,1); if (p<32) clx[p]=ci[j]; }
  __syncthreads();
  int m = cnt; if (m>32) m=32;

  // exact f32 rescore (reference arithmetic)
  __shared__ float exs[32];
  int wv = tid>>6, lane = tid&63;
  for (int c=wv; c<m; c+=4) {
    int idx = clx[c];
    float dot=0.f, ksq=0.f;
    if (idx < CAP) {
      float2 kv = reinterpret_cast<const float2*>(keys + (size_t)idx*FEAT)[lane];
      float2 qv = reinterpret_cast<const float2*>(qn  + (size_t)q  *FEAT)[lane];
      dot = kv.x*qv.x + kv.y*qv.y;
      ksq = kv.x*kv.x + kv.y*kv.y;
    }
    #pragma unroll
    for (int o=1;o<64;o<<=1){ dot += __shfl_xor(dot,o); ksq += __shfl_xor(ksq,o); }
    if (lane==0) {
      float sim = -INFINITY;
      if (idx < CAP) {
        float age = (float)(gstep0 - ts[idx]);
        sim = dot / fmaxf(sqrtf(ksq), 1e-12f) * powf(0.995f, age);
      }
      exs[c] = sim;
    }
  }
  __syncthreads();

  __shared__ int wix[K];
  if (tid < 64) {
    float sv = (tid < m) ? exs[tid] : -INFINITY;
    int   iv = (tid < m) ? clx[tid] : 0x7fffffff;
    for (int r=0;r<K;++r) {
      float bs=sv; int bi=iv;
      #pragma unroll
      for (int o=1;o<64;o<<=1){ float os=__shfl_xor(bs,o); int oi=__shfl_xor(bi,o);
        if (BET(os,oi,bs,bi)) { bs=os; bi=oi; } }
      if (tid==0) {
        out[OUT_SIMS + q*K + r] = bs;
        out[OUT_MASK + q*K + r] = (bs >= 0.0f) ? 1.0f : 0.0f;
        out[OUT_IDX  + q*K + r] = (float)bi;
        wix[r] = bi;
      }
      if (iv == bi) sv = -INFINITY;
    }
  }
  __syncthreads();
  for (int r=0;r<K;++r) {
    int fi = wix[r];
    for (int e=tid; e<ROWF; e+=256)
      out[(q*K + r)*ROWF + e] = values[(size_t)fi*ROWF + e];
  }
}

extern "C" void kernel_launch(void* const* d_in, const int* in_sizes, int n_in,
                              void* d_out, int out_size, void* d_ws, size_t ws_size,
                              hipStream_t stream) {
  const float* query  = (const float*)d_in[0];
  const float* keys   = (const float*)d_in[1];
  const float* values = (const float*)d_in[2];
  const int*   ts     = (const int*)d_in[3];
  const int*   gstep  = (const int*)d_in[4];

  float* out  = (float*)d_out;
  float* wsf  = (float*)d_ws;

  float* qn   = wsf + WS_QN;
  uint4* qF   = (uint4*)(wsf + WS_QF);
  float* psim = wsf + WS_PSIM;
  int*   pidx = (int*)(wsf + WS_PIDX);

  prep_q<<<16, 256, 0, stream>>>(query, qn, qF);
  gemm_topk3<<<NBLK, 1024, 0, stream>>>(keys, ts, gstep, qF, psim, pidx);
  merge_rescore<<<BATCH, 256, 0, stream>>>(psim, pidx, keys, qn, ts, gstep, values, out);
}

// Round 7
// 61.612 us; speedup vs baseline: 1.5387x; 1.5387x over previous
//
#include <hip/hip_runtime.h>
#include <math.h>

#define BATCH 256
#define FEAT 128
#define CAP 100000
#define ROWF 168
#define K 5
#define NBLK2 782           // blocks of 128 keys; 782*128 = 100096 >= CAP
#define NCHK 1564           // 64-key chunks (NBLK2*2)
#define SCPT 7              // ceil(NCHK/256)
#define MAXSEL 32
#define MARGIN 0.008f

// out layout (floats): retrieved [0,215040) | top_sims | valid_mask | top_idx
#define OUT_SIMS 215040
#define OUT_MASK 216320
#define OUT_IDX  217600

// ws layout (float units)
#define WS_QN    0          // 256*128 f32 normalized queries (exact rescore)
#define WS_QF    32768      // 4096 uint4 = bf16 B-fragments
#define WS_TMAX  49152      // 256*1564 f32 chunk maxima

typedef __attribute__((ext_vector_type(8))) short short8;
typedef __attribute__((ext_vector_type(4))) float f32x4;

#define BET(vs,vi,ss,ii) ((vs) > (ss) || ((vs) == (ss) && (vi) < (ii)))

__device__ __forceinline__ unsigned short f2bf(float f) {
  unsigned u = __float_as_uint(f);
  u += 0x7fffu + ((u >> 16) & 1u);     // RNE
  return (unsigned short)(u >> 16);
}
__device__ __forceinline__ unsigned pack2(float a, float b) {
  return (unsigned)f2bf(a) | ((unsigned)f2bf(b) << 16);
}

// sorted-5 insert, explicit (value desc, idx asc) tie-break
__device__ __forceinline__ void ins_cmp(float v, int k, float (&s)[5], int (&i)[5]) {
  if (BET(v,k,s[4],i[4])) {
    if (BET(v,k,s[3],i[3])) { s[4]=s[3]; i[4]=i[3];
      if (BET(v,k,s[2],i[2])) { s[3]=s[2]; i[3]=i[2];
        if (BET(v,k,s[1],i[1])) { s[2]=s[1]; i[2]=i[1];
          if (BET(v,k,s[0],i[0])) { s[1]=s[0]; i[1]=i[0]; s[0]=v; i[0]=k; }
          else { s[1]=v; i[1]=k; } }
        else { s[2]=v; i[2]=k; } }
      else { s[3]=v; i[3]=k; } }
    else { s[4]=v; i[4]=k; }
  }
}

// grid 16 (q-groups of 16), block 256. Writes f32 qn + bf16 B-fragments.
__global__ __launch_bounds__(256) void prep_q(const float* __restrict__ q,
                                              float* __restrict__ qn,
                                              uint4* __restrict__ qF) {
  int tid = threadIdx.x, qg = blockIdx.x;
  int qi = tid >> 4;             // query in group (0..15)
  int d0 = (tid & 15) * 8;
  int q_ = qg*16 + qi;
  const float4* src = reinterpret_cast<const float4*>(q + (size_t)q_*FEAT + d0);
  float4 v0 = src[0], v1 = src[1];
  float ss = v0.x*v0.x + v0.y*v0.y + v0.z*v0.z + v0.w*v0.w
           + v1.x*v1.x + v1.y*v1.y + v1.z*v1.z + v1.w*v1.w;
  ss += __shfl_xor(ss,1); ss += __shfl_xor(ss,2);
  ss += __shfl_xor(ss,4); ss += __shfl_xor(ss,8);
  float inv = 1.0f / fmaxf(sqrtf(ss), 1e-12f);
  v0.x*=inv; v0.y*=inv; v0.z*=inv; v0.w*=inv;
  v1.x*=inv; v1.y*=inv; v1.z*=inv; v1.w*=inv;
  float4* dst = reinterpret_cast<float4*>(qn + (size_t)q_*FEAT + d0);
  dst[0] = v0; dst[1] = v1;
  uint4 pk;
  pk.x = pack2(v0.x,v0.y); pk.y = pack2(v0.z,v0.w);
  pk.z = pack2(v1.x,v1.y); pk.w = pack2(v1.z,v1.w);
  int s_ = d0 >> 5, lg = (d0 >> 3) & 3;
  qF[((qg*4 + s_)*64) + lg*16 + qi] = pk;
}

// grid NBLK2 (128 keys/block), block 512 (8 waves; wave w owns q-groups 2w,2w+1).
// Stage 128 scaled bf16 keys into LDS A-frag slabs (stride 66 -> balanced
// write banks, contiguous conflict-free reads), MFMA, emit 64-key chunk maxima.
__global__ __launch_bounds__(512, 4) void gemm_max(
    const float* __restrict__ keys, const int* __restrict__ ts,
    const int* __restrict__ gstep, const uint4* __restrict__ qF,
    float* __restrict__ tmax) {
  __shared__ uint4 lds_kf[32*66];      // 8 tiles x 4 slabs, stride 66 (33 KB)
  int tid = threadIdx.x;
  int w = tid >> 6, lane = tid & 63;
  int blk = blockIdx.x;
  int kbase = blk * 128;
  int gstep0 = gstep[0];
  bool tail = (kbase + 128 > CAP);

  short8 qf0[4], qf1[4];
  #pragma unroll
  for (int s_ = 0; s_ < 4; ++s_) {
    qf0[s_] = __builtin_bit_cast(short8, qF[((2*w  )*4 + s_)*64 + lane]);
    qf1[s_] = __builtin_bit_cast(short8, qF[((2*w+1)*4 + s_)*64 + lane]);
  }

  // stage: 512 threads x 4 iters cover 128 keys x 16 dim-slices
  #pragma unroll
  for (int it = 0; it < 4; ++it) {
    int kl = it*32 + (tid >> 4);       // local key 0..127
    int dp = tid & 15;                 // 8-dim slice
    int gk = kbase + kl;
    float4 v0 = {0,0,0,0}, v1 = {0,0,0,0};
    if (gk < CAP) {
      const float4* kp = reinterpret_cast<const float4*>(keys + (size_t)gk*FEAT + dp*8);
      v0 = kp[0]; v1 = kp[1];
    }
    float ss = v0.x*v0.x+v0.y*v0.y+v0.z*v0.z+v0.w*v0.w
             + v1.x*v1.x+v1.y*v1.y+v1.z*v1.z+v1.w*v1.w;
    ss += __shfl_xor(ss,1); ss += __shfl_xor(ss,2);
    ss += __shfl_xor(ss,4); ss += __shfl_xor(ss,8);
    float scl = 0.0f;
    if (gk < CAP) {
      float age = (float)(gstep0 - ts[gk]);
      scl = exp2f(age * -0.00723157f) / fmaxf(sqrtf(ss), 1e-12f);  // approx only
    }
    uint4 pk;
    pk.x = pack2(v0.x*scl, v0.y*scl); pk.y = pack2(v0.z*scl, v0.w*scl);
    pk.z = pack2(v1.x*scl, v1.y*scl); pk.w = pack2(v1.z*scl, v1.w*scl);
    int slab = (kl >> 4)*4 + (dp >> 2);
    int slot = (dp & 3)*16 + (kl & 15);
    lds_kf[slab*66 + slot] = pk;
  }
  __syncthreads();

  float cm0[2] = {-INFINITY,-INFINITY};
  float cm1[2] = {-INFINITY,-INFINITY};

  #pragma unroll
  for (int t = 0; t < 8; ++t) {
    f32x4 acc0 = {0.f,0.f,0.f,0.f}, acc1 = {0.f,0.f,0.f,0.f};
    #pragma unroll
    for (int s_ = 0; s_ < 4; ++s_) {
      short8 a = __builtin_bit_cast(short8, lds_kf[(t*4 + s_)*66 + lane]);
      acc0 = __builtin_amdgcn_mfma_f32_16x16x32_bf16(a, qf0[s_], acc0, 0,0,0);
      acc1 = __builtin_amdgcn_mfma_f32_16x16x32_bf16(a, qf1[s_], acc1, 0,0,0);
    }
    // C/D: col=lane&15 (query), row=(lane>>4)*4+r (key)
    float m0, m1;
    if (tail) {
      int kb = kbase + t*16 + (lane>>4)*4;
      m0 = -INFINITY; m1 = -INFINITY;
      #pragma unroll
      for (int r = 0; r < 4; ++r) {
        if (kb + r < CAP) { m0 = fmaxf(m0, acc0[r]); m1 = fmaxf(m1, acc1[r]); }
      }
    } else {
      m0 = fmaxf(fmaxf(acc0[0],acc0[1]), fmaxf(acc0[2],acc0[3]));
      m1 = fmaxf(fmaxf(acc1[0],acc1[1]), fmaxf(acc1[2],acc1[3]));
    }
    m0 = fmaxf(m0, __shfl_xor(m0,16)); m0 = fmaxf(m0, __shfl_xor(m0,32));
    m1 = fmaxf(m1, __shfl_xor(m1,16)); m1 = fmaxf(m1, __shfl_xor(m1,32));
    cm0[t>>2] = fmaxf(cm0[t>>2], m0);
    cm1[t>>2] = fmaxf(cm1[t>>2], m1);
  }

  if (lane < 16) {
    int q0 = w*32 + lane, q1 = q0 + 16;
    float2 a; a.x = cm0[0]; a.y = cm0[1];
    float2 b; b.x = cm1[0]; b.y = cm1[1];
    *reinterpret_cast<float2*>(&tmax[(size_t)q0*NCHK + blk*2]) = a;
    *reinterpret_cast<float2*>(&tmax[(size_t)q1*NCHK + blk*2]) = b;
  }
}

// grid 256 (1/query), block 256: find m5a over chunk maxima -> select chunks
// >= m5a - MARGIN -> exact f32 rescore -> exact top-5 with idx tie-break.
__global__ __launch_bounds__(256) void select_rescore(
    const float* __restrict__ tmax, const float* __restrict__ keys,
    const float* __restrict__ qn, const int* __restrict__ ts,
    const int* __restrict__ gstep, const float* __restrict__ values,
    float* __restrict__ out) {
  int q = blockIdx.x, tid = threadIdx.x;
  int gstep0 = gstep[0];

  __shared__ float qrow[FEAT];
  if (tid < 32)
    reinterpret_cast<float4*>(qrow)[tid] =
        reinterpret_cast<const float4*>(qn + (size_t)q*FEAT)[tid];

  float cs[SCPT]; int ci[SCPT];
  #pragma unroll
  for (int j = 0; j < SCPT; ++j) {
    int c = tid + j*256;
    if (c < NCHK) { cs[j] = tmax[(size_t)q*NCHK + c]; ci[j] = c; }
    else { cs[j] = -INFINITY; ci[j] = 0x7fffffff; }
  }
  __syncthreads();

  __shared__ float rs_[4]; __shared__ int ri_[4];
  __shared__ float wS; __shared__ int wI;

  // phase 1: m5a = 5th largest chunk max (value with idx tie-break)
  unsigned taken = 0;
  float s5a = 0.f;
  for (int r = 0; r < K; ++r) {
    float bs = -INFINITY; int bi = 0x7fffffff;
    #pragma unroll
    for (int j = 0; j < SCPT; ++j) {
      bool live = !((taken >> j) & 1u);
      bool bet = live && BET(cs[j], ci[j], bs, bi);
      bs = bet ? cs[j] : bs; bi = bet ? ci[j] : bi;
    }
    #pragma unroll
    for (int o = 1; o < 64; o <<= 1) {
      float os = __shfl_xor(bs, o); int oi = __shfl_xor(bi, o);
      if (BET(os, oi, bs, bi)) { bs = os; bi = oi; }
    }
    if ((tid & 63) == 0) { rs_[tid>>6] = bs; ri_[tid>>6] = bi; }
    __syncthreads();
    if (tid == 0) {
      float fs = rs_[0]; int fi = ri_[0];
      #pragma unroll
      for (int ww = 1; ww < 4; ++ww)
        if (BET(rs_[ww], ri_[ww], fs, fi)) { fs = rs_[ww]; fi = ri_[ww]; }
      wS = fs; wI = fi;
    }
    __syncthreads();
    int fi = wI;
    #pragma unroll
    for (int j = 0; j < SCPT; ++j) if (ci[j] == fi) taken |= (1u << j);
    if (r == K-1) s5a = wS;
    __syncthreads();
  }

  // phase 2: select all chunks within margin
  float th = s5a - MARGIN;
  __shared__ int cnt; __shared__ int clist[MAXSEL];
  if (tid == 0) cnt = 0;
  __syncthreads();
  #pragma unroll
  for (int j = 0; j < SCPT; ++j)
    if (cs[j] >= th && ci[j] < NCHK) {
      int p = atomicAdd(&cnt, 1);
      if (p < MAXSEL) clist[p] = ci[j];
    }
  __syncthreads();
  int nsel = cnt < MAXSEL ? cnt : MAXSEL;

  // phase 3: exact f32 rescore of selected chunks (reference arithmetic)
  float bs5[5] = {-INFINITY,-INFINITY,-INFINITY,-INFINITY,-INFINITY};
  int   bi5[5] = {0x7fffffff,0x7fffffff,0x7fffffff,0x7fffffff,0x7fffffff};
  for (int kk = tid; kk < nsel*64; kk += 256) {
    int key = clist[kk >> 6]*64 + (kk & 63);
    float sim = -INFINITY;
    if (key < CAP) {
      float dot = 0.f, ksq = 0.f;
      const float4* kp = reinterpret_cast<const float4*>(keys + (size_t)key*FEAT);
      #pragma unroll
      for (int d = 0; d < 32; ++d) {
        float4 kv = kp[d];
        float4 qv = reinterpret_cast<float4*>(qrow)[d];
        dot = fmaf(kv.w,qv.w,fmaf(kv.z,qv.z,fmaf(kv.y,qv.y,fmaf(kv.x,qv.x,dot))));
        ksq = fmaf(kv.w,kv.w,fmaf(kv.z,kv.z,fmaf(kv.y,kv.y,fmaf(kv.x,kv.x,ksq))));
      }
      float age = (float)(gstep0 - ts[key]);
      sim = dot / fmaxf(sqrtf(ksq), 1e-12f) * powf(0.995f, age);
    }
    ins_cmp(sim, key, bs5, bi5);
  }

  // phase 4: block top-5 of rescored values, outputs + gather
  __shared__ int wix[K];
  unsigned taken2 = 0;
  for (int r = 0; r < K; ++r) {
    float bs = -INFINITY; int bi = 0x7fffffff;
    #pragma unroll
    for (int j = 0; j < K; ++j) {
      bool live = !((taken2 >> j) & 1u);
      bool bet = live && BET(bs5[j], bi5[j], bs, bi);
      bs = bet ? bs5[j] : bs; bi = bet ? bi5[j] : bi;
    }
    #pragma unroll
    for (int o = 1; o < 64; o <<= 1) {
      float os = __shfl_xor(bs, o); int oi = __shfl_xor(bi, o);
      if (BET(os, oi, bs, bi)) { bs = os; bi = oi; }
    }
    if ((tid & 63) == 0) { rs_[tid>>6] = bs; ri_[tid>>6] = bi; }
    __syncthreads();
    if (tid == 0) {
      float fs = rs_[0]; int fi = ri_[0];
      #pragma unroll
      for (int ww = 1; ww < 4; ++ww)
        if (BET(rs_[ww], ri_[ww], fs, fi)) { fs = rs_[ww]; fi = ri_[ww]; }
      out[OUT_SIMS + q*K + r] = fs;
      out[OUT_MASK + q*K + r] = (fs >= 0.0f) ? 1.0f : 0.0f;
      out[OUT_IDX  + q*K + r] = (float)fi;
      wix[r] = fi; wI = fi;
    }
    __syncthreads();
    int fi = wI;
    #pragma unroll
    for (int j = 0; j < K; ++j) if (bi5[j] == fi) taken2 |= (1u << j);
    __syncthreads();
  }
  for (int r = 0; r < K; ++r) {
    int fi = wix[r];
    for (int e = tid; e < ROWF; e += 256)
      out[(q*K + r)*ROWF + e] = values[(size_t)fi*ROWF + e];
  }
}

extern "C" void kernel_launch(void* const* d_in, const int* in_sizes, int n_in,
                              void* d_out, int out_size, void* d_ws, size_t ws_size,
                              hipStream_t stream) {
  const float* query  = (const float*)d_in[0];
  const float* keys   = (const float*)d_in[1];
  const float* values = (const float*)d_in[2];
  const int*   ts     = (const int*)d_in[3];
  const int*   gstep  = (const int*)d_in[4];

  float* out  = (float*)d_out;
  float* wsf  = (float*)d_ws;

  float* qn   = wsf + WS_QN;
  uint4* qF   = (uint4*)(wsf + WS_QF);
  float* tmax = wsf + WS_TMAX;

  prep_q<<<16, 256, 0, stream>>>(query, qn, qF);
  gemm_max<<<NBLK2, 512, 0, stream>>>(keys, ts, gstep, qF, tmax);
  select_rescore<<<BATCH, 256, 0, stream>>>(tmax, keys, qn, ts, gstep, values, out);
}

// Round 8
// 60.237 us; speedup vs baseline: 1.5738x; 1.0228x over previous
//
#include <hip/hip_runtime.h>
#include <math.h>

#define BATCH 256
#define FEAT 128
#define CAP 100000
#define ROWF 168
#define K 5
#define NBLK2 782           // blocks of 128 keys; 782*128 = 100096 >= CAP
#define NCHK 6256           // 16-key chunks (NBLK2*8); CAP%16==0 -> chunks fully valid or fully padded
#define SCPT 7              // ceil(NCHK/1024)
#define MAXSEL 32
#define MARGIN 0.008f

// out layout (floats): retrieved [0,215040) | top_sims | valid_mask | top_idx
#define OUT_SIMS 215040
#define OUT_MASK 216320
#define OUT_IDX  217600

// ws layout (float units)
#define WS_QN    0          // 256*128 f32 normalized queries (exact rescore)
#define WS_QF    32768      // 4096 uint4 = bf16 B-fragments
#define WS_TMAX  49152      // 256*6256 f32 chunk maxima

typedef __attribute__((ext_vector_type(8))) short short8;
typedef __attribute__((ext_vector_type(4))) float f32x4;

#define BET(vs,vi,ss,ii) ((vs) > (ss) || ((vs) == (ss) && (vi) < (ii)))

__device__ __forceinline__ unsigned short f2bf(float f) {
  unsigned u = __float_as_uint(f);
  u += 0x7fffu + ((u >> 16) & 1u);     // RNE (proven in R4-R7; margin analysis assumes RNE)
  return (unsigned short)(u >> 16);
}
__device__ __forceinline__ unsigned pack2(float a, float b) {
  return (unsigned)f2bf(a) | ((unsigned)f2bf(b) << 16);
}

// grid 16 (q-groups of 16), block 256. Writes f32 qn + bf16 B-fragments.
__global__ __launch_bounds__(256) void prep_q(const float* __restrict__ q,
                                              float* __restrict__ qn,
                                              uint4* __restrict__ qF) {
  int tid = threadIdx.x, qg = blockIdx.x;
  int qi = tid >> 4;             // query in group (0..15)
  int d0 = (tid & 15) * 8;
  int q_ = qg*16 + qi;
  const float4* src = reinterpret_cast<const float4*>(q + (size_t)q_*FEAT + d0);
  float4 v0 = src[0], v1 = src[1];
  float ss = v0.x*v0.x + v0.y*v0.y + v0.z*v0.z + v0.w*v0.w
           + v1.x*v1.x + v1.y*v1.y + v1.z*v1.z + v1.w*v1.w;
  ss += __shfl_xor(ss,1); ss += __shfl_xor(ss,2);
  ss += __shfl_xor(ss,4); ss += __shfl_xor(ss,8);
  float inv = 1.0f / fmaxf(sqrtf(ss), 1e-12f);
  v0.x*=inv; v0.y*=inv; v0.z*=inv; v0.w*=inv;
  v1.x*=inv; v1.y*=inv; v1.z*=inv; v1.w*=inv;
  float4* dst = reinterpret_cast<float4*>(qn + (size_t)q_*FEAT + d0);
  dst[0] = v0; dst[1] = v1;
  uint4 pk;
  pk.x = pack2(v0.x,v0.y); pk.y = pack2(v0.z,v0.w);
  pk.z = pack2(v1.x,v1.y); pk.w = pack2(v1.z,v1.w);
  int s_ = d0 >> 5, lg = (d0 >> 3) & 3;
  qF[((qg*4 + s_)*64) + lg*16 + qi] = pk;
}

// grid NBLK2 (128 keys/block), block 512 (8 waves; wave w owns q-groups 2w,2w+1).
// Stage 128 scaled bf16 keys into LDS A-frag slabs (stride 66 -> balanced
// write banks, conflict-free reads), MFMA, emit per-16-key-tile maxima.
__global__ __launch_bounds__(512, 4) void gemm_max(
    const float* __restrict__ keys, const int* __restrict__ ts,
    const int* __restrict__ gstep, const uint4* __restrict__ qF,
    float* __restrict__ tmax) {
  __shared__ uint4 lds_kf[32*66];      // 8 tiles x 4 slabs, stride 66 (33 KB)
  int tid = threadIdx.x;
  int w = tid >> 6, lane = tid & 63;
  int blk = blockIdx.x;
  int kbase = blk * 128;
  int gstep0 = gstep[0];
  bool tail = (kbase + 128 > CAP);

  short8 qf0[4], qf1[4];
  #pragma unroll
  for (int s_ = 0; s_ < 4; ++s_) {
    qf0[s_] = __builtin_bit_cast(short8, qF[((2*w  )*4 + s_)*64 + lane]);
    qf1[s_] = __builtin_bit_cast(short8, qF[((2*w+1)*4 + s_)*64 + lane]);
  }

  // stage: 512 threads x 4 iters cover 128 keys x 16 dim-slices
  #pragma unroll
  for (int it = 0; it < 4; ++it) {
    int kl = it*32 + (tid >> 4);       // local key 0..127
    int dp = tid & 15;                 // 8-dim slice
    int gk = kbase + kl;
    float4 v0 = {0,0,0,0}, v1 = {0,0,0,0};
    if (gk < CAP) {
      const float4* kp = reinterpret_cast<const float4*>(keys + (size_t)gk*FEAT + dp*8);
      v0 = kp[0]; v1 = kp[1];
    }
    float ss = v0.x*v0.x+v0.y*v0.y+v0.z*v0.z+v0.w*v0.w
             + v1.x*v1.x+v1.y*v1.y+v1.z*v1.z+v1.w*v1.w;
    ss += __shfl_xor(ss,1); ss += __shfl_xor(ss,2);
    ss += __shfl_xor(ss,4); ss += __shfl_xor(ss,8);
    float scl = 0.0f;
    if (gk < CAP) {
      float age = (float)(gstep0 - ts[gk]);
      scl = exp2f(age * -0.00723157f) / fmaxf(sqrtf(ss), 1e-12f);  // approx only
    }
    uint4 pk;
    pk.x = pack2(v0.x*scl, v0.y*scl); pk.y = pack2(v0.z*scl, v0.w*scl);
    pk.z = pack2(v1.x*scl, v1.y*scl); pk.w = pack2(v1.z*scl, v1.w*scl);
    int slab = (kl >> 4)*4 + (dp >> 2);
    int slot = (dp & 3)*16 + (kl & 15);
    lds_kf[slab*66 + slot] = pk;
  }
  __syncthreads();

  float tm0[8], tm1[8];

  #pragma unroll
  for (int t = 0; t < 8; ++t) {
    f32x4 acc0 = {0.f,0.f,0.f,0.f}, acc1 = {0.f,0.f,0.f,0.f};
    #pragma unroll
    for (int s_ = 0; s_ < 4; ++s_) {
      short8 a = __builtin_bit_cast(short8, lds_kf[(t*4 + s_)*66 + lane]);
      acc0 = __builtin_amdgcn_mfma_f32_16x16x32_bf16(a, qf0[s_], acc0, 0,0,0);
      acc1 = __builtin_amdgcn_mfma_f32_16x16x32_bf16(a, qf1[s_], acc1, 0,0,0);
    }
    // C/D: col=lane&15 (query), row=(lane>>4)*4+r (key)
    float m0, m1;
    if (tail) {
      int kb = kbase + t*16 + (lane>>4)*4;
      m0 = -INFINITY; m1 = -INFINITY;
      #pragma unroll
      for (int r = 0; r < 4; ++r) {
        if (kb + r < CAP) { m0 = fmaxf(m0, acc0[r]); m1 = fmaxf(m1, acc1[r]); }
      }
    } else {
      m0 = fmaxf(fmaxf(acc0[0],acc0[1]), fmaxf(acc0[2],acc0[3]));
      m1 = fmaxf(fmaxf(acc1[0],acc1[1]), fmaxf(acc1[2],acc1[3]));
    }
    m0 = fmaxf(m0, __shfl_xor(m0,16)); m0 = fmaxf(m0, __shfl_xor(m0,32));
    m1 = fmaxf(m1, __shfl_xor(m1,16)); m1 = fmaxf(m1, __shfl_xor(m1,32));
    tm0[t] = m0; tm1[t] = m1;
  }

  if (lane < 16) {
    int q0 = w*32 + lane, q1 = q0 + 16;
    float4 a0 = {tm0[0],tm0[1],tm0[2],tm0[3]};
    float4 a1 = {tm0[4],tm0[5],tm0[6],tm0[7]};
    float4 b0 = {tm1[0],tm1[1],tm1[2],tm1[3]};
    float4 b1 = {tm1[4],tm1[5],tm1[6],tm1[7]};
    float4* p0 = reinterpret_cast<float4*>(&tmax[(size_t)q0*NCHK + blk*8]);
    float4* p1 = reinterpret_cast<float4*>(&tmax[(size_t)q1*NCHK + blk*8]);
    p0[0] = a0; p0[1] = a1;
    p1[0] = b0; p1[1] = b1;
  }
}

// grid 256 (1/query), block 1024 (16 waves): m5a over chunk maxima -> select
// chunks >= m5a - MARGIN -> exact f32 rescore (coalesced, 4 thr/key) -> top-5.
__global__ __launch_bounds__(1024) void select_rescore(
    const float* __restrict__ tmax, const float* __restrict__ keys,
    const float* __restrict__ qn, const int* __restrict__ ts,
    const int* __restrict__ gstep, const float* __restrict__ values,
    float* __restrict__ out) {
  int q = blockIdx.x, tid = threadIdx.x;
  int w = tid >> 6, lane = tid & 63;
  int gstep0 = gstep[0];

  __shared__ float qrow[FEAT];
  if (tid < 32)
    reinterpret_cast<float4*>(qrow)[tid] =
        reinterpret_cast<const float4*>(qn + (size_t)q*FEAT)[tid];

  float cs[SCPT]; int ci[SCPT];
  #pragma unroll
  for (int j = 0; j < SCPT; ++j) {
    int c = tid + j*1024;
    if (c < NCHK) { cs[j] = tmax[(size_t)q*NCHK + c]; ci[j] = c; }
    else { cs[j] = -INFINITY; ci[j] = 0x7fffffff; }
  }
  __syncthreads();

  __shared__ float redS[16]; __shared__ int redI[16];
  __shared__ float wS; __shared__ int wI;

  // phase 1: m5a = 5th largest chunk max
  unsigned taken = 0;
  float s5a = 0.f;
  for (int r = 0; r < K; ++r) {
    float bs = -INFINITY; int bi = 0x7fffffff;
    #pragma unroll
    for (int j = 0; j < SCPT; ++j) {
      bool live = !((taken >> j) & 1u);
      bool bet = live && BET(cs[j], ci[j], bs, bi);
      bs = bet ? cs[j] : bs; bi = bet ? ci[j] : bi;
    }
    #pragma unroll
    for (int o = 1; o < 64; o <<= 1) {
      float os = __shfl_xor(bs, o); int oi = __shfl_xor(bi, o);
      if (BET(os, oi, bs, bi)) { bs = os; bi = oi; }
    }
    if (lane == 0) { redS[w] = bs; redI[w] = bi; }
    __syncthreads();
    if (tid == 0) {
      float fs = redS[0]; int fi = redI[0];
      #pragma unroll
      for (int ww = 1; ww < 16; ++ww)
        if (BET(redS[ww], redI[ww], fs, fi)) { fs = redS[ww]; fi = redI[ww]; }
      wS = fs; wI = fi;
    }
    __syncthreads();
    int fi = wI;
    #pragma unroll
    for (int j = 0; j < SCPT; ++j) if (ci[j] == fi) taken |= (1u << j);
    if (r == K-1) s5a = wS;
  }

  // phase 2: select all chunks within margin of m5a
  float th = s5a - MARGIN;
  __shared__ int cnt; __shared__ int clist[MAXSEL];
  if (tid == 0) cnt = 0;
  __syncthreads();
  #pragma unroll
  for (int j = 0; j < SCPT; ++j)
    if (cs[j] >= th && ci[j] < NCHK) {
      int p = atomicAdd(&cnt, 1);
      if (p < MAXSEL) clist[p] = ci[j];
    }
  __syncthreads();
  int nsel = cnt < MAXSEL ? cnt : MAXSEL;

  // phase 3: exact f32 rescore, 4 threads/key (wave reads 16 consecutive
  // keys = 8 KB contiguous). Reference arithmetic: dot/max(||k||,eps)*0.995^age.
  __shared__ float exs[MAXSEL*16];
  for (int s4 = tid; s4 < nsel*64; s4 += 1024) {
    int slot = s4 >> 2, part = s4 & 3;
    int key = clist[slot >> 4]*16 + (slot & 15);
    float dot = 0.f, ksq = 0.f;
    if (key < CAP) {
      const float4* kp = reinterpret_cast<const float4*>(keys + (size_t)key*FEAT + part*32);
      const float4* qp = reinterpret_cast<float4*>(qrow) + part*8;
      #pragma unroll
      for (int d = 0; d < 8; ++d) {
        float4 kv = kp[d];
        float4 qv = qp[d];
        dot = fmaf(kv.w,qv.w,fmaf(kv.z,qv.z,fmaf(kv.y,qv.y,fmaf(kv.x,qv.x,dot))));
        ksq = fmaf(kv.w,kv.w,fmaf(kv.z,kv.z,fmaf(kv.y,kv.y,fmaf(kv.x,kv.x,ksq))));
      }
    }
    dot += __shfl_xor(dot,1); dot += __shfl_xor(dot,2);
    ksq += __shfl_xor(ksq,1); ksq += __shfl_xor(ksq,2);
    if (part == 0) {
      float sim = -INFINITY;
      if (key < CAP) {
        float age = (float)(gstep0 - ts[key]);
        sim = dot / fmaxf(sqrtf(ksq), 1e-12f) * powf(0.995f, age);
      }
      exs[slot] = sim;
    }
  }
  __syncthreads();

  // phase 4: exact top-5 over <=512 rescored values + outputs + gather
  __shared__ int wix[K];
  float sv = -INFINITY; int iv = 0x7fffffff;
  if (tid < nsel*16) {
    sv = exs[tid];
    iv = clist[tid >> 4]*16 + (tid & 15);
  }
  for (int r = 0; r < K; ++r) {
    float bs = sv; int bi = iv;
    #pragma unroll
    for (int o = 1; o < 64; o <<= 1) {
      float os = __shfl_xor(bs, o); int oi = __shfl_xor(bi, o);
      if (BET(os, oi, bs, bi)) { bs = os; bi = oi; }
    }
    if (lane == 0) { redS[w] = bs; redI[w] = bi; }
    __syncthreads();
    if (tid == 0) {
      float fs = redS[0]; int fi = redI[0];
      #pragma unroll
      for (int ww = 1; ww < 16; ++ww)
        if (BET(redS[ww], redI[ww], fs, fi)) { fs = redS[ww]; fi = redI[ww]; }
      out[OUT_SIMS + q*K + r] = fs;
      out[OUT_MASK + q*K + r] = (fs >= 0.0f) ? 1.0f : 0.0f;
      out[OUT_IDX  + q*K + r] = (float)fi;
      wix[r] = fi; wI = fi;
    }
    __syncthreads();
    if (iv == wI) sv = -INFINITY;   // winner unique by key idx
  }
  for (int idx = tid; idx < K*ROWF; idx += 1024) {
    int r = idx / ROWF, e = idx - r*ROWF;
    out[(q*K + r)*ROWF + e] = values[(size_t)wix[r]*ROWF + e];
  }
}

extern "C" void kernel_launch(void* const* d_in, const int* in_sizes, int n_in,
                              void* d_out, int out_size, void* d_ws, size_t ws_size,
                              hipStream_t stream) {
  const float* query  = (const float*)d_in[0];
  const float* keys   = (const float*)d_in[1];
  const float* values = (const float*)d_in[2];
  const int*   ts     = (const int*)d_in[3];
  const int*   gstep  = (const int*)d_in[4];

  float* out  = (float*)d_out;
  float* wsf  = (float*)d_ws;

  float* qn   = wsf + WS_QN;
  uint4* qF   = (uint4*)(wsf + WS_QF);
  float* tmax = wsf + WS_TMAX;

  prep_q<<<16, 256, 0, stream>>>(query, qn, qF);
  gemm_max<<<NBLK2, 512, 0, stream>>>(keys, ts, gstep, qF, tmax);
  select_rescore<<<BATCH, 1024, 0, stream>>>(tmax, keys, qn, ts, gstep, values, out);
}